// Round 11
// baseline (126.315 us; speedup 1.0000x reference)
//
#include <hip/hip_runtime.h>
#include <math.h>

// Problem constants
#define BATCH 8
#define NVERT 8192
#define NPD   64
#define NCELL 4096             // 64*64 grid cells per batch
#define SPLITS 64              // blocks per batch
#define JPB   (NVERT / SPLITS) // 128 vertices per block
#define KR    32               // vertices per MFMA round (K of one mfma)
#define ROUNDS (JPB / KR)      // 4
#define NFIN  8                // finisher blocks per batch (sp < NFIN)
#define MAGIC 0x5A17C0DEu      // != 0xAAAAAAAA poison, != 0

#ifndef M_PI
#define M_PI 3.14159265358979323846
#endif

// ws layout (floats / uints)
#define TOTPART_OFF  0         // float totpart[512]
#define FLAGS_OFF    1024      // uint  flags[512]
#define PARTIALS_OFF 4096      // float partials[512*4096] = 8 MB

typedef __attribute__((ext_vector_type(8))) short  bf16x8;
typedef __attribute__((ext_vector_type(4))) float  f32x4;

static __device__ __forceinline__ float fast_exp2(float x) {
#if __has_builtin(__builtin_amdgcn_exp2f)
    return __builtin_amdgcn_exp2f(x);
#else
    return exp2f(x);
#endif
}

// RNE float->bf16 pair pack: low 16 = a, high 16 = b.
static __device__ __forceinline__ unsigned int pack_bf16(float a, float b) {
    unsigned int ua = __float_as_uint(a), ub = __float_as_uint(b);
    ua += 0x7fffu + ((ua >> 16) & 1u);
    ub += 0x7fffu + ((ub >> 16) & 1u);
    return (ua >> 16) | (ub & 0xffff0000u);
}

// ---------------------------------------------------------------------------
// Single dispatch: sigma + MFMA separable KDE + release-flag; 8 finisher
// blocks per batch poll the 64 flags, then normalize+write 512 cells each.
// Grid = BATCH*SPLITS = 512 blocks x 256 threads (4 waves, ~22 KB LDS ->
// all co-resident at 2 blocks/CU). Non-finishers exit after their flag.
// ---------------------------------------------------------------------------
__global__ __launch_bounds__(256) void kde_one(const float* __restrict__ T,
                                               float* __restrict__ totpart,
                                               unsigned int* __restrict__ flags,
                                               float* __restrict__ partials,
                                               float* __restrict__ out) {
    const int b   = blockIdx.x >> 6;           // / SPLITS
    const int sp  = blockIdx.x & (SPLITS - 1);
    const int j0  = sp * JPB;
    const int tid = threadIdx.x;
    const int w    = tid >> 6;                 // wave id 0..3
    const int lane = tid & 63;

    __shared__ __align__(16) unsigned short exT[2][64][40];  // 10240 B
    __shared__ __align__(16) unsigned short eyT[2][64][40];  // 10240 B
    __shared__ float2 tj[JPB];                 // this block's vertex slice
    __shared__ float  red[4][4];
    __shared__ float  bcast[2];                // kexp2, scale

    // ---- phase 0: sigma over the full batch (redundant per block) ----
    const float4* T4 = reinterpret_cast<const float4*>(T + (size_t)b * NVERT * 2);
    float sx = 0.f, sx2 = 0.f, sy = 0.f, sy2 = 0.f;
    for (int q = tid; q < NVERT / 2; q += 256) {   // 2 vertices per float4
        float4 v = T4[q];
        sx += v.x + v.z;
        sy += v.y + v.w;
        sx2 += v.x * v.x + v.z * v.z;
        sy2 += v.y * v.y + v.w * v.w;
        int local = 2 * q - j0;                    // even when in range
        if ((unsigned)local < (unsigned)JPB)
            *reinterpret_cast<float4*>(&tj[local]) = v;
    }
    for (int off = 32; off; off >>= 1) {
        sx  += __shfl_down(sx,  off);  sx2 += __shfl_down(sx2, off);
        sy  += __shfl_down(sy,  off);  sy2 += __shfl_down(sy2, off);
    }
    if (lane == 0) { red[w][0] = sx; red[w][1] = sx2; red[w][2] = sy; red[w][3] = sy2; }
    __syncthreads();
    if (tid == 0) {
        double tsx = 0, tsx2 = 0, tsy = 0, tsy2 = 0;
        for (int i = 0; i < 4; ++i) {
            tsx += red[i][0]; tsx2 += red[i][1]; tsy += red[i][2]; tsy2 += red[i][3];
        }
        const double N = (double)NVERT;
        double varx = (tsx2 - tsx * tsx / N) / (N - 1.0);
        double vary = (tsy2 - tsy * tsy / N) / (N - 1.0);
        double sigma = 0.5 * (sqrt(varx) + sqrt(vary));
        const double BD = 1.0 / 63.0;
        if (sigma < BD) sigma = BD;
        const double C2 = pow(2.0, -13.0 / 3.0);   // C^2, C = NV^(-1/6)
        double s2 = sigma * sigma;
        bcast[0] = (float)(-0.5 / C2 / (s2 * 0.69314718055994530942)); // exp2 coeff
        bcast[1] = (float)(1.0 / (2.0 * M_PI * C2) / (s2 * N));        // CF*s^-2/NV
    }
    __syncthreads();
    const float kexp2 = bcast[0];

    // ---- staging constants ----
    const float xg   = (float)lane * (1.0f / 63.0f);
    const int   jh   = (w >> 1) << 4;          // 0 or 16
    const bool  isY  = (w & 1);

#define STAGE(R, BUF)                                                       \
    {                                                                       \
        unsigned short (*dstT)[40] = isY ? eyT[BUF] : exT[BUF];             \
        _Pragma("unroll")                                                   \
        for (int jp = 0; jp < 8; ++jp) {                                    \
            int jl = jh + jp * 2;                                           \
            float4 tt = *reinterpret_cast<const float4*>(&tj[(R) * KR + jl]);\
            float tv0 = isY ? tt.y : tt.x;                                  \
            float tv1 = isY ? tt.w : tt.z;                                  \
            float d0 = xg - tv0, d1 = xg - tv1;                             \
            float e0 = fast_exp2(kexp2 * d0 * d0);                          \
            float e1 = fast_exp2(kexp2 * d1 * d1);                          \
            *reinterpret_cast<unsigned int*>(&dstT[lane][jl]) =             \
                pack_bf16(e0, e1);                                          \
        }                                                                   \
    }

    // ---- phase 1: MFMA main loop, double-buffered, 1 barrier per round ----
    const int col16 = lane & 15;
    const int kq    = lane >> 4;               // k-quarter 0..3
    f32x4 acc[4];
#pragma unroll
    for (int ni = 0; ni < 4; ++ni) acc[ni] = (f32x4){0.f, 0.f, 0.f, 0.f};

    STAGE(0, 0);                               // prologue: round 0 -> buf 0
    for (int r = 0; r < ROUNDS; ++r) {
        __syncthreads();                       // round r staged; buf r+1 free
        if (r + 1 < ROUNDS) STAGE(r + 1, (r + 1) & 1);
        const int buf = r & 1;
        bf16x8 af = *reinterpret_cast<const bf16x8*>(&exT[buf][(w << 4) + col16][kq << 3]);
#pragma unroll
        for (int ni = 0; ni < 4; ++ni) {
            bf16x8 bfr = *reinterpret_cast<const bf16x8*>(&eyT[buf][(ni << 4) + col16][kq << 3]);
            acc[ni] = __builtin_amdgcn_mfma_f32_16x16x32_bf16(af, bfr, acc[ni], 0, 0, 0);
        }
    }

    // ---- phase 2: write block partial + block total ----
    // D layout (m89-verified): col = lane&15, row = (lane>>4)*4 + reg.
    float* dst = partials + (size_t)blockIdx.x * NCELL;
    float tsum = 0.f;
    const int rowbase = (w << 4) + (kq << 2);  // gx of reg r = rowbase + r
#pragma unroll
    for (int ni = 0; ni < 4; ++ni) {
#pragma unroll
        for (int r = 0; r < 4; ++r) {
            dst[(rowbase + r) * 64 + (ni << 4) + col16] = acc[ni][r];
            tsum += acc[ni][r];
        }
    }
    for (int off = 32; off; off >>= 1) tsum += __shfl_down(tsum, off);
    if (lane == 0) red[w][0] = tsum;
    __syncthreads();
    if (tid == 0)
        totpart[blockIdx.x] = (red[0][0] + red[1][0]) + (red[2][0] + red[3][0]);

    // ---- release: partial + total visible device-wide, then flag ----
    __threadfence();
    __syncthreads();
    if (tid == 0) atomicExch(&flags[blockIdx.x], MAGIC);

    if (sp >= NFIN) return;                    // non-finishers done

    // ---- phase 3 (finisher): wait for the batch's 64 flags, then finish
    //      cells [sp*512 .. sp*512+511] of batch b.
    if (tid < 64) {
        const unsigned int* f = flags + (b << 6);
        while (__hip_atomic_load(&f[tid], __ATOMIC_ACQUIRE,
                                 __HIP_MEMORY_SCOPE_AGENT) != MAGIC)
            __builtin_amdgcn_s_sleep(2);
    }
    __syncthreads();
    __threadfence();                           // acquire: see partials/totpart

    // batch total (wave 0), broadcast via LDS
    if (tid < 64) {
        float v = totpart[(b << 6) + tid];
        for (int off = 32; off; off >>= 1) v += __shfl_down(v, off);
        if (tid == 0) red[0][0] = v;
    }
    __syncthreads();
    const float tot   = red[0][0];
    const float scale = bcast[1];
    const float denom = fmaxf(tot * scale, 1e-5f);

    // 512 cells: 2 per thread, 4 independent sum chains over 64 slices
    const int c0 = sp * 512 + tid;
    const int c1 = c0 + 256;
    const float* p = partials + (size_t)(b << 6) * NCELL;
    float s0a = 0.f, s0b = 0.f, s1a = 0.f, s1b = 0.f;
#pragma unroll 8
    for (int s = 0; s < 64; s += 2) {
        s0a += p[(size_t)s * NCELL + c0];
        s0b += p[(size_t)(s + 1) * NCELL + c0];
        s1a += p[(size_t)s * NCELL + c1];
        s1b += p[(size_t)(s + 1) * NCELL + c1];
    }
    out[b * NCELL + c0] = ((s0a + s0b) * scale) / denom;
    out[b * NCELL + c1] = ((s1a + s1b) * scale) / denom;
}

// ---------------------------------------------------------------------------
extern "C" void kernel_launch(void* const* d_in, const int* in_sizes, int n_in,
                              void* d_out, int out_size, void* d_ws, size_t ws_size,
                              hipStream_t stream) {
    const float* T = (const float*)d_in[0];   // [B, NV, 2] f32
    // d_in[1] (S) is a deterministic 64x64 meshgrid in [0,1]^2 — derived inline.

    float*        ws       = (float*)d_ws;
    float*        totpart  = ws + TOTPART_OFF;
    unsigned int* flags    = (unsigned int*)(ws + FLAGS_OFF);
    float*        partials = ws + PARTIALS_OFF;

    kde_one<<<BATCH * SPLITS, 256, 0, stream>>>(T, totpart, flags, partials,
                                                (float*)d_out);
}

// Round 13
// 97.434 us; speedup vs baseline: 1.2964x; 1.2964x over previous
//
#include <hip/hip_runtime.h>
#include <math.h>

// Problem constants
#define BATCH  8
#define NVERT  8192
#define NCELL  4096            // 64*64 grid cells per batch
#define TPB    16              // tile-blocks per batch (4x4 tiles of 16x16)
#define KR     32              // vertices per MFMA round
#define KCH    (NVERT / 4)     // 2048 vertices per wave (K-split across 4 waves)
#define ROUNDS (KCH / KR)      // 64
#define POISON 0xAAAAAAAAu

#ifndef M_PI
#define M_PI 3.14159265358979323846
#endif

typedef __attribute__((ext_vector_type(8))) short  bf16x8;
typedef __attribute__((ext_vector_type(4))) float  f32x4;

static __device__ __forceinline__ float fast_exp2(float x) {
#if __has_builtin(__builtin_amdgcn_exp2f)
    return __builtin_amdgcn_exp2f(x);
#else
    return exp2f(x);
#endif
}

// RNE float->bf16 pair pack: low 16 = a, high 16 = b.
static __device__ __forceinline__ unsigned int pack_bf16(float a, float b) {
    unsigned int ua = __float_as_uint(a), ub = __float_as_uint(b);
    ua += 0x7fffu + ((ua >> 16) & 1u);
    ub += 0x7fffu + ((ub >> 16) & 1u);
    return (ua >> 16) | (ub & 0xffff0000u);
}

// ---------------------------------------------------------------------------
// Single worker dispatch, NO polling anywhere.
// Grid = BATCH*TPB = 128 blocks x 256 threads (4 waves, 1 block/CU).
// Block (b, t): 16x16 cell tile (rows tr0.., cols tc0..) over the FULL
// K=8192 vertices. Wave w owns K-chunk [w*2048, (w+1)*2048): per 32-vertex
// round it stages its own wave-private ex[16 rows][32 k] / ey[16 cols][32 k]
// bf16 panels in LDS (same-wave produce->consume through memory: compiler
// orders via lgkmcnt, no cross-wave hazard -> zero barriers) and issues
// 1x mfma_f32_16x16x32_bf16. Cross-wave K-sum in LDS, raw (unnormalized)
// tile written to out.
// Finish: fence + atomicAdd(cnt[b]); the LAST block of the batch (old==15;
// cnt zeroed by a prepended 32-byte memset) re-reads the 4096 raw values,
// total = their exact sum (denominator bias cancels vs bf16 numerator),
// normalizes in place. Single atomic per block, no loops on memory.
// ---------------------------------------------------------------------------
__global__ __launch_bounds__(256) void kde_last(const float* __restrict__ T,
                                                unsigned int* __restrict__ cnt,
                                                float* __restrict__ out) {
    const int blk = blockIdx.x;
    const int b   = blk >> 4;
    const int t   = blk & 15;
    const int tr0 = (t >> 2) << 4;             // tile x-row base
    const int tc0 = (t & 3) << 4;              // tile y-col base
    const int tid = threadIdx.x;
    const int w    = tid >> 6;                 // wave id 0..3
    const int lane = tid & 63;

    __shared__ __align__(16) unsigned short es[4][2][16][40]; // [wave][ex/ey][row][k]
    __shared__ float red[4][4];
    __shared__ float gsum[4][16][17];          // cross-wave K-sum (pad 17)
    __shared__ float bc[3];                    // kexp2, scale, factor
    __shared__ unsigned int lastflag;

    // ---- phase 0: sigma over the full batch (redundant per block) ----
    const float4* T4 = reinterpret_cast<const float4*>(T + (size_t)b * NVERT * 2);
    float sx = 0.f, sx2 = 0.f, sy = 0.f, sy2 = 0.f;
    for (int q = tid; q < NVERT / 2; q += 256) {   // 2 vertices per float4
        float4 v = T4[q];
        sx += v.x + v.z;
        sy += v.y + v.w;
        sx2 += v.x * v.x + v.z * v.z;
        sy2 += v.y * v.y + v.w * v.w;
    }
    for (int off = 32; off; off >>= 1) {
        sx  += __shfl_down(sx,  off);  sx2 += __shfl_down(sx2, off);
        sy  += __shfl_down(sy,  off);  sy2 += __shfl_down(sy2, off);
    }
    if (lane == 0) { red[w][0] = sx; red[w][1] = sx2; red[w][2] = sy; red[w][3] = sy2; }
    __syncthreads();
    if (tid == 0) {
        double tsx = 0, tsx2 = 0, tsy = 0, tsy2 = 0;
        for (int i = 0; i < 4; ++i) {
            tsx += red[i][0]; tsx2 += red[i][1]; tsy += red[i][2]; tsy2 += red[i][3];
        }
        const double N = (double)NVERT;
        double varx = (tsx2 - tsx * tsx / N) / (N - 1.0);
        double vary = (tsy2 - tsy * tsy / N) / (N - 1.0);
        double sigma = 0.5 * (sqrt(varx) + sqrt(vary));
        const double BD = 1.0 / 63.0;
        if (sigma < BD) sigma = BD;
        const double C2 = pow(2.0, -13.0 / 3.0);   // C^2, C = NV^(-1/6)
        double s2 = sigma * sigma;
        bc[0] = (float)(-0.5 / C2 / (s2 * 0.69314718055994530942)); // exp2 coeff
        bc[1] = (float)(1.0 / (2.0 * M_PI * C2) / (s2 * N));        // CF*s^-2/NV
    }
    __syncthreads();
    const float kexp2 = bc[0];

    // ---- staging constants (hoisted) ----
    // Lanes 0-31: ex plane (tile rows); lanes 32-63: ey plane (tile cols).
    // Within a plane: vp = vertex-pair 0..15, rb = row base 0 or 8; each lane
    // stages rows rb..rb+7 for its vertex pair.
    const int   vp    = lane & 15;
    const int   plane = lane >> 5;
    const int   rb    = ((lane >> 4) & 1) * 8;
    const int   base0 = plane ? tc0 : tr0;
    float c1[8], m2[8];
#pragma unroll
    for (int i = 0; i < 8; ++i) {
        float xg = (float)(base0 + rb + i) * (1.0f / 63.0f);
        m2[i] = -2.0f * kexp2 * xg;            // exp arg = m2*t + (kexp2*xg^2 + kexp2*t^2)
        c1[i] = kexp2 * xg * xg;
    }

    // ---- phase 1: full-K MFMA loop, wave-private staging, ZERO barriers ----
    unsigned short (*exw)[40] = es[w][0];
    unsigned short (*eyw)[40] = es[w][1];
    unsigned short (*dstT)[40] = es[w][plane];
    const float4* T4v = reinterpret_cast<const float4*>(T) + (size_t)b * 4096 + w * 1024;

    const int frow = lane & 15;                // fragment row/col
    const int kq   = lane >> 4;                // k-quarter 0..3
    f32x4 acc = (f32x4){0.f, 0.f, 0.f, 0.f};

    for (int r = 0; r < ROUNDS; ++r) {
        float4 tt = T4v[r * 16 + vp];          // verts (2j, 2j+1)
        float t0 = plane ? tt.y : tt.x;
        float t1 = plane ? tt.w : tt.z;
        float kt20 = kexp2 * t0 * t0;
        float kt21 = kexp2 * t1 * t1;
#pragma unroll
        for (int i = 0; i < 8; ++i) {
            float e0 = fast_exp2(fmaf(m2[i], t0, c1[i] + kt20));
            float e1 = fast_exp2(fmaf(m2[i], t1, c1[i] + kt21));
            *reinterpret_cast<unsigned int*>(&dstT[rb + i][vp * 2]) = pack_bf16(e0, e1);
        }
        // same-wave DS ordering: compiler inserts lgkmcnt between the writes
        // above and the dependent reads below (aliasing through es).
        bf16x8 af = *reinterpret_cast<const bf16x8*>(&exw[frow][kq << 3]);
        bf16x8 bf = *reinterpret_cast<const bf16x8*>(&eyw[frow][kq << 3]);
        acc = __builtin_amdgcn_mfma_f32_16x16x32_bf16(af, bf, acc, 0, 0, 0);
    }

    // ---- phase 2: cross-wave K-sum, write raw tile ----
    // D layout (m89-verified): col = lane&15, row = (lane>>4)*4 + reg.
#pragma unroll
    for (int ri = 0; ri < 4; ++ri)
        gsum[w][(kq << 2) + ri][frow] = acc[ri];
    __syncthreads();
    const int rr = tid >> 4, cc = tid & 15;
    const float raw = (gsum[0][rr][cc] + gsum[1][rr][cc])
                    + (gsum[2][rr][cc] + gsum[3][rr][cc]);
    out[b * NCELL + (tr0 + rr) * 64 + tc0 + cc] = raw;

    // ---- release + last-block election (single atomic, NO polling) ----
    __threadfence();
    __syncthreads();
    if (tid == 0) {
        unsigned int old = atomicAdd(&cnt[b], 1u);
        lastflag = (old == 15u || old == POISON + 15u) ? 1u : 0u;
    }
    __syncthreads();
    if (!lastflag) return;

    // ---- phase 3 (last block of batch only): total + normalize in place ----
    __threadfence();                           // acquire: see all 16 tiles
    float* ob = out + b * NCELL;
    float v[16];
    float s = 0.f;
#pragma unroll
    for (int i = 0; i < 16; ++i) {             // coalesced, deterministic order
        v[i] = ob[i * 256 + tid];
        s += v[i];
    }
    for (int off = 32; off; off >>= 1) s += __shfl_down(s, off);
    if (lane == 0) red[w][0] = s;
    __syncthreads();
    if (tid == 0) {
        const float tot   = (red[0][0] + red[1][0]) + (red[2][0] + red[3][0]);
        const float scale = bc[1];
        const float denom = fmaxf(tot * scale, 1e-5f);
        bc[2] = scale / denom;
    }
    __syncthreads();
    const float factor = bc[2];
#pragma unroll
    for (int i = 0; i < 16; ++i)
        ob[i * 256 + tid] = v[i] * factor;
}

// ---------------------------------------------------------------------------
extern "C" void kernel_launch(void* const* d_in, const int* in_sizes, int n_in,
                              void* d_out, int out_size, void* d_ws, size_t ws_size,
                              hipStream_t stream) {
    const float* T = (const float*)d_in[0];   // [B, NV, 2] f32
    // d_in[1] (S) is a deterministic 64x64 meshgrid in [0,1]^2 — derived inline.

    unsigned int* cnt = (unsigned int*)d_ws;  // 8 counters
    // Zero the counters every call: removes any assumption about d_ws's
    // initial contents (only documented as 0xAA before TIMED launches).
    hipMemsetAsync(cnt, 0, BATCH * sizeof(unsigned int), stream);
    kde_last<<<BATCH * TPB, 256, 0, stream>>>(T, cnt, (float*)d_out);
}